// Round 1
// baseline (65.723 us; speedup 1.0000x reference)
//
#include <hip/hip_runtime.h>

#define N_HYP 128

__global__ __launch_bounds__(128) void margin_loss_kernel(
    const float* __restrict__ scores, const int* __restrict__ werRank,
    float* __restrict__ out) {
  const int b = blockIdx.x;
  const int j = threadIdx.x;
  __shared__ float s[N_HYP];
  const size_t base = (size_t)b * N_HYP;
  // gather scores into WER-rank order
  s[j] = scores[base + (size_t)werRank[base + j]];
  __syncthreads();

  const float sj = s[j];
  float acc = 0.0f;
#pragma unroll 4
  for (int k = j + 1; k < N_HYP; ++k) {
    float d = s[k] - sj;
    acc += fmaxf(d, 0.0f);
  }
  // mean over the neg set for this j (j == N-1 contributes nothing)
  float val = (j < N_HYP - 1) ? acc / (float)(N_HYP - 1 - j) : 0.0f;

  // wave (64-lane) reduction
  for (int off = 32; off > 0; off >>= 1)
    val += __shfl_down(val, off, 64);

  __shared__ float wsum[2];
  if ((j & 63) == 0) wsum[j >> 6] = val;
  __syncthreads();
  if (j == 0) atomicAdd(out, wsum[0] + wsum[1]);
}

extern "C" void kernel_launch(void* const* d_in, const int* in_sizes, int n_in,
                              void* d_out, int out_size, void* d_ws, size_t ws_size,
                              hipStream_t stream) {
  const float* scores  = (const float*)d_in[0];
  const int*   werRank = (const int*)d_in[2];
  float* out = (float*)d_out;
  const int B = in_sizes[0] / N_HYP;

  // d_out is poisoned once before timing and never re-poisoned; zero it each call.
  hipMemsetAsync(d_out, 0, sizeof(float), stream);
  margin_loss_kernel<<<B, N_HYP, 0, stream>>>(scores, werRank, out);
}

// Round 2
// 17.465 us; speedup vs baseline: 3.7631x; 3.7631x over previous
//
#include <hip/hip_runtime.h>

#define N_HYP 128
#define BLOCK 256
#define WAVES 4  // BLOCK / 64

// One wave per utterance. Each lane owns k = lane and k = lane+64 and
// accumulates sum_{j<k} w_j * relu(s_k - s_j) over a UNIFORM j-loop
// (j < k handled by predicated weight -> no divergence).
__global__ __launch_bounds__(BLOCK) void margin_loss_k1(
    const float* __restrict__ scores, const int* __restrict__ werRank,
    float* __restrict__ partials, int B) {
  __shared__ float s_lds[WAVES][N_HYP];
  __shared__ float w_lds[N_HYP];
  __shared__ float wave_sum[WAVES];

  const int tid  = threadIdx.x;
  const int lane = tid & 63;
  const int wid  = tid >> 6;

  if (tid < N_HYP - 1) w_lds[tid] = 1.0f / (float)(N_HYP - 1 - tid);

  const int u = blockIdx.x * WAVES + wid;  // one utterance per wave
  const int valid = (u < B);
  const size_t base = (size_t)(valid ? u : 0) * N_HYP;

  // Gather scores into WER-rank order (rank loads coalesced; score gather
  // stays within one 512B row -> L1-local).
  {
    const int r0 = werRank[base + lane];
    const int r1 = werRank[base + lane + 64];
    s_lds[wid][lane]      = scores[base + r0];
    s_lds[wid][lane + 64] = scores[base + r1];
  }
  __syncthreads();

  const int k0 = lane;
  const int k1 = lane + 64;
  const float sk0 = s_lds[wid][k0];
  const float sk1 = s_lds[wid][k1];

  float acc = 0.0f;
#pragma unroll 4
  for (int j = 0; j < N_HYP - 1; ++j) {
    const float sj = s_lds[wid][j];  // wave-uniform broadcast
    const float wj = w_lds[j];       // wave-uniform broadcast
    const float d0 = fmaxf(sk0 - sj, 0.0f);
    const float d1 = fmaxf(sk1 - sj, 0.0f);
    acc = fmaf((j < k0) ? wj : 0.0f, d0, acc);
    acc = fmaf((j < k1) ? wj : 0.0f, d1, acc);
  }
  if (!valid) acc = 0.0f;

  // wave (64-lane) reduction, then cross-wave combine; NO global atomics.
  for (int off = 32; off > 0; off >>= 1) acc += __shfl_down(acc, off, 64);
  if (lane == 0) wave_sum[wid] = acc;
  __syncthreads();
  if (tid == 0)
    partials[blockIdx.x] = wave_sum[0] + wave_sum[1] + wave_sum[2] + wave_sum[3];
}

__global__ __launch_bounds__(256) void margin_loss_k2(
    const float* __restrict__ partials, int n, float* __restrict__ out) {
  float v = 0.0f;
  for (int i = threadIdx.x; i < n; i += 256) v += partials[i];
  for (int off = 32; off > 0; off >>= 1) v += __shfl_down(v, off, 64);
  __shared__ float ws[4];
  if ((threadIdx.x & 63) == 0) ws[threadIdx.x >> 6] = v;
  __syncthreads();
  if (threadIdx.x == 0) out[0] = ws[0] + ws[1] + ws[2] + ws[3];
}

extern "C" void kernel_launch(void* const* d_in, const int* in_sizes, int n_in,
                              void* d_out, int out_size, void* d_ws, size_t ws_size,
                              hipStream_t stream) {
  const float* scores  = (const float*)d_in[0];
  const int*   werRank = (const int*)d_in[2];
  float* out = (float*)d_out;
  float* partials = (float*)d_ws;
  const int B = in_sizes[0] / N_HYP;

  const int nblocks = (B + WAVES - 1) / WAVES;  // 1024 for B=4096
  margin_loss_k1<<<nblocks, BLOCK, 0, stream>>>(scores, werRank, partials, B);
  margin_loss_k2<<<1, 256, 0, stream>>>(partials, nblocks, out);
}

// Round 3
// 14.534 us; speedup vs baseline: 4.5221x; 1.2017x over previous
//
#include <hip/hip_runtime.h>

#define N_HYP 128
#define BLOCK 256
#define WAVES 4  // BLOCK / 64

// One wave per utterance. Lane owns j0=lane and j1=lane+64; loops k over all
// 128 positions via float4 LDS broadcasts. Weight 1/(N-1-j) applied ONCE at
// the end (factored out of the pair loop). No __syncthreads anywhere: each
// wave touches only its own LDS row and writes its own partial.
__global__ __launch_bounds__(BLOCK) void margin_loss_k1(
    const float* __restrict__ scores, const int* __restrict__ werRank,
    float* __restrict__ partials, int B) {
  __shared__ float s_lds[WAVES][N_HYP];

  const int tid  = threadIdx.x;
  const int lane = tid & 63;
  const int wid  = tid >> 6;
  const int u = blockIdx.x * WAVES + wid;
  const bool valid = (u < B);
  const size_t base = (size_t)(valid ? u : 0) * N_HYP;

  // Gather scores into WER-rank order (rank loads coalesced; score gather
  // within one 512B row -> L1-local).
  const int r0 = werRank[base + lane];
  const int r1 = werRank[base + lane + 64];
  const float sj0 = scores[base + r0];
  const float sj1 = scores[base + r1];
  s_lds[wid][lane]      = sj0;
  s_lds[wid][lane + 64] = sj1;
  // wave-local LDS row: compiler-inserted lgkmcnt orders write->read.

  const float4* srow = (const float4*)&s_lds[wid][0];
  float a0 = 0.f, b0 = 0.f, a1 = 0.f, b1 = 0.f;

  // k in [0,64): only the j0 term can be active, conditional on k > lane.
#pragma unroll
  for (int q = 0; q < 16; ++q) {
    const float4 sv = srow[q];
    const int k = q * 4;
    a0 += (k + 0 > lane) ? fmaxf(sv.x - sj0, 0.f) : 0.f;
    b0 += (k + 1 > lane) ? fmaxf(sv.y - sj0, 0.f) : 0.f;
    a0 += (k + 2 > lane) ? fmaxf(sv.z - sj0, 0.f) : 0.f;
    b0 += (k + 3 > lane) ? fmaxf(sv.w - sj0, 0.f) : 0.f;
  }
  // k in [64,128): j0 term unconditional; j1 term conditional on k-64 > lane.
#pragma unroll
  for (int q = 16; q < 32; ++q) {
    const float4 sv = srow[q];
    const int km = q * 4 - 64;
    a0 += fmaxf(sv.x - sj0, 0.f);
    b0 += fmaxf(sv.y - sj0, 0.f);
    a0 += fmaxf(sv.z - sj0, 0.f);
    b0 += fmaxf(sv.w - sj0, 0.f);
    a1 += (km + 0 > lane) ? fmaxf(sv.x - sj1, 0.f) : 0.f;
    b1 += (km + 1 > lane) ? fmaxf(sv.y - sj1, 0.f) : 0.f;
    a1 += (km + 2 > lane) ? fmaxf(sv.z - sj1, 0.f) : 0.f;
    b1 += (km + 3 > lane) ? fmaxf(sv.w - sj1, 0.f) : 0.f;
  }

  const float acc0 = a0 + b0;
  const float acc1 = a1 + b1;
  const float w0 = 1.0f / (float)(N_HYP - 1 - lane);        // j0 = lane <= 63
  const float w1 = (lane < 63) ? 1.0f / (float)(63 - lane)  // j1 = lane+64
                               : 0.0f;                      // j1 = 127: empty neg set
  float val = acc0 * w0 + acc1 * w1;

  for (int off = 32; off > 0; off >>= 1) val += __shfl_down(val, off, 64);
  if (lane == 0 && valid) partials[u] = val;
}

__global__ __launch_bounds__(256) void margin_loss_k2(
    const float* __restrict__ p, int n, float* __restrict__ out) {
  float v = 0.f;
  const int n4 = n >> 2;
  const float4* p4 = (const float4*)p;
  for (int i = threadIdx.x; i < n4; i += 256) {
    const float4 t = p4[i];
    v += (t.x + t.y) + (t.z + t.w);
  }
  for (int i = (n & ~3) + threadIdx.x; i < n; i += 256) v += p[i];
  for (int off = 32; off > 0; off >>= 1) v += __shfl_down(v, off, 64);
  __shared__ float ws[4];
  if ((threadIdx.x & 63) == 0) ws[threadIdx.x >> 6] = v;
  __syncthreads();
  if (threadIdx.x == 0) out[0] = (ws[0] + ws[1]) + (ws[2] + ws[3]);
}

extern "C" void kernel_launch(void* const* d_in, const int* in_sizes, int n_in,
                              void* d_out, int out_size, void* d_ws, size_t ws_size,
                              hipStream_t stream) {
  const float* scores  = (const float*)d_in[0];
  const int*   werRank = (const int*)d_in[2];
  float* out = (float*)d_out;
  float* partials = (float*)d_ws;
  const int B = in_sizes[0] / N_HYP;

  const int nblocks = (B + WAVES - 1) / WAVES;
  margin_loss_k1<<<nblocks, BLOCK, 0, stream>>>(scores, werRank, partials, B);
  margin_loss_k2<<<1, 256, 0, stream>>>(partials, B, out);
}